// Round 2
// baseline (117.085 us; speedup 1.0000x reference)
//
#include <hip/hip_runtime.h>

// VQ-VAE quantization, R11. MI355X gfx950.
// x: [131072, 64] f32; emb: [512, 64] f32.
// d_out: quantized_st [8388608] | loss [1] | perplexity [1].
//
// R11 structure: ONE compute kernel + one 16.5 KB hipMemsetAsync.
//  - vq_prep is gone: each block converts emb -> bf16 frag plane + (1+norm)
//    directly into its LDS during staging (emb is 128 KB, L2/L3-broadcast-hot;
//    conversion overlaps the x-register loads, all before barrier 1).
//  - R10's tail regression fixed: histogram atomics spread over 8 ghist
//    copies (blockIdx&7) -> 8x less cache-line contention at the coherence
//    point; last block (atomic ticket) sums the 8 copies with independent
//    pipelined atomic reads and emits loss+perplexity.
//  - Argmin: u32 pack (score_bits & ~0x1FF | code), score = (1+||e||^2) - 2*dot
//    in (0.7,1.3) > 0, so uint order == float order; 9 dropped mantissa bits
//    = 6e-5 quantization, far below the ~0.018 inter-code spread and the
//    tolerated 3e-4 bf16 score error. Same numerics as R10 (passed, absmax 2.0).
//
// Rows-per-wave: each wave owns 32 rows x all 512 codes; bf16 codebook in
// LDS (64KB, fragment order) -> ~70.7 KB LDS/block, 2 blocks/CU, 16 waves/CU.

#define D      64
#define M      512
#define N_VEC  131072
#define N_ELEM 8388608

typedef __attribute__((ext_vector_type(8))) short short8;
typedef __attribute__((ext_vector_type(4))) float f32x4;

// ws bytes: [0,4) loss f32 | [32,36) ticket u32 | [64, 64+16384) u32 ghist[8][512]
// (all zeroed by the memset each iteration)

static __device__ __forceinline__ unsigned short f2bf(float f) {
    unsigned u = __float_as_uint(f);
    return (unsigned short)((u + 0x7FFFu + ((u >> 16) & 1u)) >> 16);  // RNE
}

__global__ __launch_bounds__(512, 4)   // 8 waves/block, 4 waves/EU -> 2 blocks/CU
void vq_main(const float* __restrict__ x, const float* __restrict__ emb,
             float* __restrict__ out, float* __restrict__ loss_sum,
             unsigned* __restrict__ ticket, unsigned* __restrict__ ghist) {
    __shared__ __align__(16) short sE[32768];   // 64 KB bf16 codebook, frag order
    __shared__ float sBn[M];                    // 1 + ||e||^2
    __shared__ unsigned sCode[256];
    __shared__ unsigned sHist[M];
    __shared__ float sRed[8];
    __shared__ unsigned sLast;

    const int tid = threadIdx.x;
    const int w = tid >> 6, lane = tid & 63;
    const int q = lane >> 4, col = lane & 15;
    const int rowBase = blockIdx.x * 256 + w * 32;   // wave-private 32 rows

    // ---- stage codebook: emb (f32, L2-hot broadcast) -> bf16 frag plane in
    //      LDS + exact (1+norm). Thread tid owns code c=tid. Two 32-wide
    //      halves keep live registers at 8 float4s. Norm order matches the
    //      reference's sequential k+=4 four-lane tree exactly. ----
    {
        const int c = tid, ct = c >> 4, ccol = c & 15;
        float s0 = 0.f, s1 = 0.f, s2 = 0.f, s3 = 0.f;
#pragma unroll
        for (int s = 0; s < 2; ++s) {
            float4 v[8];
#pragma unroll
            for (int m = 0; m < 8; ++m)
                v[m] = *(const float4*)(emb + c * D + s * 32 + m * 4);
#pragma unroll
            for (int m = 0; m < 8; ++m) {
                s0 = fmaf(v[m].x, v[m].x, s0); s1 = fmaf(v[m].y, v[m].y, s1);
                s2 = fmaf(v[m].z, v[m].z, s2); s3 = fmaf(v[m].w, v[m].w, s3);
            }
#pragma unroll
            for (int qq = 0; qq < 4; ++qq) {
                const float ff[8] = {v[qq*2].x, v[qq*2].y, v[qq*2].z, v[qq*2].w,
                                     v[qq*2+1].x, v[qq*2+1].y, v[qq*2+1].z, v[qq*2+1].w};
                short8 h;
#pragma unroll
                for (int j = 0; j < 8; ++j) h[j] = (short)f2bf(ff[j]);
                *(short8*)&sE[(((ct * 2 + s) * 64) + qq * 16 + ccol) * 8] = h;
            }
        }
        sBn[c] = 1.0f + ((s0 + s1) + (s2 + s3));   // +1: keep packed scores > 0
        sHist[c] = 0u;
    }

    // ---- x rows (A-frag pattern: lane holds row=col / 16+col, k = s*32+q*8+j) ----
    float4 xc[8];
    {
        const float* p0 = x + (size_t)(rowBase + col) * D + q * 8;
        const float* p1 = x + (size_t)(rowBase + 16 + col) * D + q * 8;
        xc[0] = *(const float4*)(p0);      xc[1] = *(const float4*)(p0 + 4);
        xc[2] = *(const float4*)(p0 + 32); xc[3] = *(const float4*)(p0 + 36);
        xc[4] = *(const float4*)(p1);      xc[5] = *(const float4*)(p1 + 4);
        xc[6] = *(const float4*)(p1 + 32); xc[7] = *(const float4*)(p1 + 36);
    }

    // ---- bf16 x-frags (single plane). No x-norm: it is a per-row constant
    //      offset to every score and cannot change the argmin. ----
    short8 XH[2][2];
#pragma unroll
    for (int p = 0; p < 2; ++p) {
        float f[16] = {xc[p*4+0].x, xc[p*4+0].y, xc[p*4+0].z, xc[p*4+0].w,
                       xc[p*4+1].x, xc[p*4+1].y, xc[p*4+1].z, xc[p*4+1].w,
                       xc[p*4+2].x, xc[p*4+2].y, xc[p*4+2].z, xc[p*4+2].w,
                       xc[p*4+3].x, xc[p*4+3].y, xc[p*4+3].z, xc[p*4+3].w};
#pragma unroll
        for (int j = 0; j < 8; ++j) {
            XH[p][0][j] = (short)f2bf(f[j]);
            XH[p][1][j] = (short)f2bf(f[8 + j]);
        }
    }

    __syncthreads();   // barrier 1: sE/sBn/sHist visible

    // ---- all 32 code-tiles: A=codes (LDS frags), B=x (regs), 4 MFMA/tile.
    //      packed u32 min; ascending scan keeps first-argmin ties ----
    unsigned best0 = 0xFFFFFFFFu, best1 = 0xFFFFFFFFu;
#pragma unroll 4
    for (int t = 0; t < 32; ++t) {
        const int fb = t * 1024 + lane * 8;   // shorts
        short8 Eh0 = *(const short8*)&sE[fb];
        short8 Eh1 = *(const short8*)&sE[fb + 512];
        f32x4 Bn4 = *(const f32x4*)&sBn[t * 16 + q * 4];

        f32x4 a1 = {0.f, 0.f, 0.f, 0.f};
        a1 = __builtin_amdgcn_mfma_f32_16x16x32_bf16(Eh0, XH[0][0], a1, 0, 0, 0);
        a1 = __builtin_amdgcn_mfma_f32_16x16x32_bf16(Eh1, XH[0][1], a1, 0, 0, 0);
        f32x4 b1 = {0.f, 0.f, 0.f, 0.f};
        b1 = __builtin_amdgcn_mfma_f32_16x16x32_bf16(Eh0, XH[1][0], b1, 0, 0, 0);
        b1 = __builtin_amdgcn_mfma_f32_16x16x32_bf16(Eh1, XH[1][1], b1, 0, 0, 0);

        const int cb = t * 16 + q * 4;
#pragma unroll
        for (int r = 0; r < 4; ++r) {
            float sc0 = fmaf(-2.0f, a1[r], Bn4[r]);
            float sc1 = fmaf(-2.0f, b1[r], Bn4[r]);
            unsigned p0 = (__float_as_uint(sc0) & 0xFFFFFE00u) | (unsigned)(cb + r);
            unsigned p1 = (__float_as_uint(sc1) & 0xFFFFFE00u) | (unsigned)(cb + r);
            best0 = p0 < best0 ? p0 : best0;
            best1 = p1 < best1 ? p1 : best1;
        }
    }

    // ---- cross-q reduce (u32 min; scores > 0 so uint order == float order) ----
    {
        unsigned o;
        o = __shfl_xor(best0, 16, 64); best0 = o < best0 ? o : best0;
        o = __shfl_xor(best0, 32, 64); best0 = o < best0 ? o : best0;
        o = __shfl_xor(best1, 16, 64); best1 = o < best1 ? o : best1;
        o = __shfl_xor(best1, 32, 64); best1 = o < best1 ? o : best1;
    }
    if (q == 0) {   // winners for rows w*32+col and w*32+16+col
        const unsigned c0 = best0 & 511u, c1 = best1 & 511u;
        sCode[w * 32 + col] = c0;
        sCode[w * 32 + 16 + col] = c1;
        atomicAdd(&sHist[c0], 1u);
        atomicAdd(&sHist[c1], 1u);
    }

    // ---- epilogue: wave-private 32 rows, coalesced (same-wave LDS RAW on
    //      sCode is waitcnt-ordered, no barrier needed) ----
    float lacc = 0.f;
#pragma unroll 2
    for (int i = 0; i < 8; ++i) {
        const int rr = i * 4 + q;            // 0..31
        const unsigned code = sCode[w * 32 + rr];
        const size_t a = (size_t)(rowBase + rr) * D + col * 4;
        const float4 xv = *(const float4*)(x + a);       // L1/L2-warm
        const float4 qv = *(const float4*)(emb + (size_t)code * D + col * 4);
        const float e0 = xv.x - qv.x, e1 = xv.y - qv.y, e2 = xv.z - qv.z, e3 = xv.w - qv.w;
        lacc = fmaf(e0, e0, lacc); lacc = fmaf(e1, e1, lacc);
        lacc = fmaf(e2, e2, lacc); lacc = fmaf(e3, e3, lacc);
        float4 o;  // out = fl(x + fl(q - x)) == fl(x - fl(x - q)) bit-exactly
        o.x = xv.x - e0; o.y = xv.y - e1; o.z = xv.z - e2; o.w = xv.w - e3;
        *(float4*)(out + a) = o;
    }
#pragma unroll
    for (int off = 32; off > 0; off >>= 1) lacc += __shfl_down(lacc, off, 64);
    if (lane == 0) sRed[w] = lacc;
    __syncthreads();   // barrier 2: sHist + sRed complete

    // ---- merge block hist into 8-way-spread global copies (device atomics;
    //      128 hot cache lines instead of R10's 16), block loss ----
    {
        const unsigned h = sHist[tid];
        if (h) atomicAdd(&ghist[((unsigned)blockIdx.x & 7u) * 512u + tid], h);
    }
    if (tid == 0) {
        float s = ((sRed[0] + sRed[1]) + (sRed[2] + sRed[3]))
                + ((sRed[4] + sRed[5]) + (sRed[6] + sRed[7]));
        atomicAdd(loss_sum, s);
    }
    __syncthreads();   // barrier 3: all waves' atomics complete (vmcnt drained)

    if (tid == 0) {
        __threadfence();                      // order this block's ops before ticket
        sLast = (atomicAdd(ticket, 1u) == 511u) ? 1u : 0u;
    }
    __syncthreads();   // barrier 4: sLast visible (uniform)

    if (sLast) {
        // ---- last block: perplexity + final loss (device otherwise idle).
        //      Reads via atomic RMW -> coherence point, immune to stale L2;
        //      the 8 reads per thread are independent and pipeline. ----
        unsigned cnt = 0;
#pragma unroll
        for (int k = 0; k < 8; ++k) cnt += atomicAdd(&ghist[k * 512 + tid], 0u);
        const float p = (float)cnt * (1.0f / 131072.0f);
        float term = p * logf(p + 1e-10f);
#pragma unroll
        for (int off = 32; off > 0; off >>= 1) term += __shfl_down(term, off, 64);
        if (lane == 0) sRed[w] = term;
        __syncthreads();
        if (tid == 0) {
            float s = 0.f;
#pragma unroll
            for (int ww = 0; ww < 8; ++ww) s += sRed[ww];
            const float L = atomicAdd(loss_sum, 0.0f);   // total incl. own block
            out[N_ELEM]     = 0.25f * (L * (1.0f / 8388608.0f));
            out[N_ELEM + 1] = expf(-s);
        }
    }
}

extern "C" void kernel_launch(void* const* d_in, const int* in_sizes, int n_in,
                              void* d_out, int out_size, void* d_ws, size_t ws_size,
                              hipStream_t stream) {
    (void)in_sizes; (void)n_in; (void)out_size; (void)ws_size;
    const float* x   = (const float*)d_in[0];
    const float* emb = (const float*)d_in[1];
    float* out = (float*)d_out;

    float*    loss   = (float*)d_ws;
    unsigned* ticket = (unsigned*)((char*)d_ws + 32);
    unsigned* ghist  = (unsigned*)((char*)d_ws + 64);

    // zero loss + ticket + ghist[8][512] (16448 B) in one capturable memset
    hipMemsetAsync(d_ws, 0, 64 + 8 * 512 * sizeof(unsigned), stream);

    vq_main<<<dim3(512), dim3(512), 0, stream>>>(x, emb, out, loss, ticket, ghist);
}